// Round 5
// baseline (91.028 us; speedup 1.0000x reference)
//
#include <hip/hip_runtime.h>

// Problem constants (match reference)
#define B_SZ   2
#define T_CTX  1024
#define E_IN   256
#define D_QK   64
#define DV_OUT 64
#define NROWS  (B_SZ * T_CTX)
#define RPB    8   // rows per proj block (one per wave, 512 threads)

// ---------------------------------------------------------------------------
// Kernel 1: projections, 8 rows per block, one row per wave (512 threads).
//   q = relu(x@Wq+bq); k = relu(x@Wk+bk); v = x@Wv+bv
//   qpb = q@W1[:64] + b1   (row-major [row][d])
//   kpt = (k@W1[64:])^T    (TRANSPOSED: [d][row])
// Grid = 256 blocks = exactly 1 block/CU (16 waves/CU).
// ---------------------------------------------------------------------------
__global__ __launch_bounds__(512) void proj_kernel(
    const float* __restrict__ x,
    const float* __restrict__ Wq, const float* __restrict__ bq,
    const float* __restrict__ Wk, const float* __restrict__ bk,
    const float* __restrict__ Wv, const float* __restrict__ bv,
    const float* __restrict__ W1, const float* __restrict__ b1,
    float* __restrict__ qpb, float* __restrict__ kpt, float* __restrict__ v)
{
    __shared__ float xs[RPB * E_IN];
    __shared__ float qs[RPB * D_QK];
    __shared__ float ks[RPB * D_QK];
    __shared__ float kps[RPB * D_QK];

    const int row0 = blockIdx.x * RPB;
    const int t    = threadIdx.x;

    // stage 8 x-rows: 2048 floats via one float4 per thread
    *(float4*)&xs[4 * t] = *(const float4*)&x[(size_t)row0 * E_IN + 4 * t];
    __syncthreads();

    const int d = t & 63;
    const int r = t >> 6;                  // wave -> row (0..7)
    const float* xrow = &xs[r * E_IN];

    float aq0 = 0.f, aq1 = 0.f, ak0 = 0.f, ak1 = 0.f, av0 = 0.f, av1 = 0.f;
    #pragma unroll 8
    for (int e = 0; e < E_IN; e += 2) {
        float x0 = xrow[e], x1 = xrow[e + 1];
        aq0 += x0 * Wq[(e)     * D_QK   + d];
        aq1 += x1 * Wq[(e + 1) * D_QK   + d];
        ak0 += x0 * Wk[(e)     * D_QK   + d];
        ak1 += x1 * Wk[(e + 1) * D_QK   + d];
        av0 += x0 * Wv[(e)     * DV_OUT + d];
        av1 += x1 * Wv[(e + 1) * DV_OUT + d];
    }
    qs[r * D_QK + d] = fmaxf(aq0 + aq1 + bq[d], 0.f);
    ks[r * D_QK + d] = fmaxf(ak0 + ak1 + bk[d], 0.f);
    v[(size_t)(row0 + r) * DV_OUT + d] = av0 + av1 + bv[d];
    __syncthreads();

    const float* qrow = &qs[r * D_QK];
    const float* krow = &ks[r * D_QK];
    float ap0 = 0.f, ap1 = 0.f, bp0 = 0.f, bp1 = 0.f;
    #pragma unroll 8
    for (int e = 0; e < D_QK; e += 2) {
        ap0 += qrow[e]     * W1[(e)            * D_QK + d];
        ap1 += qrow[e + 1] * W1[(e + 1)        * D_QK + d];
        bp0 += krow[e]     * W1[(D_QK + e)     * D_QK + d];
        bp1 += krow[e + 1] * W1[(D_QK + e + 1) * D_QK + d];
    }
    qpb[(size_t)(row0 + r) * D_QK + d] = ap0 + ap1 + b1[d];
    kps[r * D_QK + d] = bp0 + bp1;
    __syncthreads();

    // transposed kp write: 8 consecutive rows = 32B per d
    if (t < D_QK) {
        float4 k0 = make_float4(kps[0 * D_QK + t], kps[1 * D_QK + t],
                                kps[2 * D_QK + t], kps[3 * D_QK + t]);
        float4 k1 = make_float4(kps[4 * D_QK + t], kps[5 * D_QK + t],
                                kps[6 * D_QK + t], kps[7 * D_QK + t]);
        *(float4*)&kpt[(size_t)t * NROWS + row0]     = k0;
        *(float4*)&kpt[(size_t)t * NROWS + row0 + 4] = k1;
    }
}

// ---------------------------------------------------------------------------
// Kernel 2: one query row per block, TRANSPOSED kp, 2048 blocks = 8 blocks/CU
// (full 32-wave occupancy; __launch_bounds__(256,8) pins VGPR <= 64).
// Grid is fully co-resident, so the i-mapping is swizzled to make each CU's
// 8-block family (blk = c, c+256, ..., c+1792) have CONSTANT total work:
//   k=0: i=c        k=1: i=256+c     k=2: i=1023-c    k=3: i=767-c
// (sum of n over k = 2050 for every c; bijective on [0,1024)).
// Thread t owns j-quad [4t, 4t+3]; d-loop reads kpt[d][base+4t..] as float4
// -> wave reads 1KB contiguous per instruction.
// ---------------------------------------------------------------------------
__global__ __launch_bounds__(256, 8) void attn_kernel(
    const float* __restrict__ qpb, const float* __restrict__ kpt,
    const float* __restrict__ v,
    const float* __restrict__ W2, const float* __restrict__ b2,
    float* __restrict__ out)
{
    __shared__ float q1s[D_QK], w2s[D_QK];
    __shared__ float scp[T_CTX];
    __shared__ float red[8];
    __shared__ float part[4][DV_OUT];

    const int blk = blockIdx.x;
    const int b   = blk >> 10;
    const int u   = blk & 1023;
    const int kf  = u >> 8;
    const int c   = u & 255;
    const int i   = (kf < 2) ? ((kf << 8) | c) : (1023 - ((kf & 1) << 8) - c);
    const int n   = i + 1;
    const int t    = threadIdx.x;
    const int lane = t & 63;
    const int wave = t >> 6;
    const size_t base = (size_t)b * T_CTX;

    if (t < D_QK) {
        q1s[t] = qpb[(base + i) * D_QK + t];
        w2s[t] = W2[t];
    }
    __syncthreads();

    const float bias2 = b2[0];
    const int j0 = 4 * t;
    float a0 = 0.f, a1 = 0.f, a2 = 0.f, a3 = 0.f;
    const float* kpb = kpt + base + j0;

#define ACC(kv, qc, wc) do {                   \
    a0 += fmaxf(qc + kv.x, 0.f) * wc;          \
    a1 += fmaxf(qc + kv.y, 0.f) * wc;          \
    a2 += fmaxf(qc + kv.z, 0.f) * wc;          \
    a3 += fmaxf(qc + kv.w, 0.f) * wc; } while (0)

    if (j0 < n) {
        #pragma unroll
        for (int dd = 0; dd < D_QK; dd += 4) {
            float4 qv = *(const float4*)&q1s[dd];
            float4 wv = *(const float4*)&w2s[dd];
            float4 k0 = *(const float4*)(kpb + (size_t)(dd + 0) * NROWS);
            float4 k1 = *(const float4*)(kpb + (size_t)(dd + 1) * NROWS);
            float4 k2 = *(const float4*)(kpb + (size_t)(dd + 2) * NROWS);
            float4 k3 = *(const float4*)(kpb + (size_t)(dd + 3) * NROWS);
            ACC(k0, qv.x, wv.x);
            ACC(k1, qv.y, wv.y);
            ACC(k2, qv.z, wv.z);
            ACC(k3, qv.w, wv.w);
        }
    }
#undef ACC

    float s0v = (j0 + 0 < n) ? bias2 + a0 : -INFINITY;
    float s1v = (j0 + 1 < n) ? bias2 + a1 : -INFINITY;
    float s2v = (j0 + 2 < n) ? bias2 + a2 : -INFINITY;
    float s3v = (j0 + 3 < n) ? bias2 + a3 : -INFINITY;

    // ---- block max ----
    float ml = fmaxf(fmaxf(s0v, s1v), fmaxf(s2v, s3v));
    #pragma unroll
    for (int o = 32; o > 0; o >>= 1) ml = fmaxf(ml, __shfl_xor(ml, o, 64));
    if (lane == 0) red[wave] = ml;
    __syncthreads();
    const float m = fmaxf(fmaxf(red[0], red[1]), fmaxf(red[2], red[3]));

    // ---- exp (registers), store, block sum ----
    float p0 = __expf(s0v - m), p1 = __expf(s1v - m);
    float p2 = __expf(s2v - m), p3 = __expf(s3v - m);
    *(float4*)&scp[j0] = make_float4(p0, p1, p2, p3);   // masked -> 0
    float l = (p0 + p1) + (p2 + p3);
    #pragma unroll
    for (int o = 32; o > 0; o >>= 1) l += __shfl_xor(l, o, 64);
    if (lane == 0) red[4 + wave] = l;
    __syncthreads();
    const float denom = (red[4] + red[5]) + (red[6] + red[7]);

    // ---- PV: float2 over dv, 2 rows per wave-iter via half-wave split ----
    const int half = lane >> 5;                 // row within pair
    const int dp   = (lane & 31) * 2;           // dv pair
    float xa = 0.f, xb = 0.f;
    int j = wave * 2;
    for (; j + 1 < n; j += 8) {
        float2 vc = *(const float2*)&v[(base + j + half) * DV_OUT + dp];
        float wc  = scp[j + half];
        xa += wc * vc.x; xb += wc * vc.y;
    }
    if (j < n && half == 0) {                   // leftover single row
        float2 vc = *(const float2*)&v[(base + j) * DV_OUT + dp];
        float wc  = scp[j];
        xa += wc * vc.x; xb += wc * vc.y;
    }
    xa += __shfl_xor(xa, 32, 64);
    xb += __shfl_xor(xb, 32, 64);
    if (half == 0) *(float2*)&part[wave][dp] = make_float2(xa, xb);
    __syncthreads();
    if (t < DV_OUT) {
        out[(base + i) * DV_OUT + t] =
            ((part[0][t] + part[1][t]) + (part[2][t] + part[3][t])) / denom;
    }
}

extern "C" void kernel_launch(void* const* d_in, const int* in_sizes, int n_in,
                              void* d_out, int out_size, void* d_ws, size_t ws_size,
                              hipStream_t stream) {
    const float* x  = (const float*)d_in[0];
    const float* Wq = (const float*)d_in[1];
    const float* bq = (const float*)d_in[2];
    const float* Wk = (const float*)d_in[3];
    const float* bk = (const float*)d_in[4];
    const float* Wv = (const float*)d_in[5];
    const float* bv = (const float*)d_in[6];
    const float* W1 = (const float*)d_in[7];
    const float* b1 = (const float*)d_in[8];
    const float* W2 = (const float*)d_in[9];
    const float* b2 = (const float*)d_in[10];
    float* out = (float*)d_out;

    float* ws  = (float*)d_ws;
    float* qpb = ws;                              // NROWS * D_QK   (row-major)
    float* kpt = ws + (size_t)NROWS * D_QK;       // D_QK * NROWS   (TRANSPOSED)
    float* vv  = ws + (size_t)2 * NROWS * D_QK;   // NROWS * DV_OUT (row-major)

    proj_kernel<<<NROWS / RPB, 512, 0, stream>>>(x, Wq, bq, Wk, bk, Wv, bv,
                                                 W1, b1, qpb, kpt, vv);
    attn_kernel<<<B_SZ * T_CTX, 256, 0, stream>>>(qpb, kpt, vv, W2, b2, out);
}

// Round 6
// 73.130 us; speedup vs baseline: 1.2447x; 1.2447x over previous
//
#include <hip/hip_runtime.h>

// Problem constants (match reference)
#define B_SZ   2
#define T_CTX  1024
#define E_IN   256
#define D_QK   64
#define DV_OUT 64
#define NROWS  (B_SZ * T_CTX)
#define RPB    8    // rows per proj block (one per wave, 512 threads)
#define QT     4    // queries per attn block
#define NTILES (T_CTX / QT)   // 256 tiles per batch

// ---------------------------------------------------------------------------
// Kernel 1: projections, 8 rows per block, one row per wave (512 threads).
//   q = relu(x@Wq+bq); k = relu(x@Wk+bk); v = x@Wv+bv
//   qpb = q@W1[:64] + b1   (row-major [row][d])
//   kpt = (k@W1[64:])^T    (TRANSPOSED: [d][row])
// ---------------------------------------------------------------------------
__global__ __launch_bounds__(512) void proj_kernel(
    const float* __restrict__ x,
    const float* __restrict__ Wq, const float* __restrict__ bq,
    const float* __restrict__ Wk, const float* __restrict__ bk,
    const float* __restrict__ Wv, const float* __restrict__ bv,
    const float* __restrict__ W1, const float* __restrict__ b1,
    float* __restrict__ qpb, float* __restrict__ kpt, float* __restrict__ v)
{
    __shared__ float xs[RPB * E_IN];
    __shared__ float qs[RPB * D_QK];
    __shared__ float ks[RPB * D_QK];
    __shared__ float kps[RPB * D_QK];

    const int row0 = blockIdx.x * RPB;
    const int t    = threadIdx.x;

    // stage 8 x-rows: 2048 floats via one float4 per thread
    *(float4*)&xs[4 * t] = *(const float4*)&x[(size_t)row0 * E_IN + 4 * t];
    __syncthreads();

    const int d = t & 63;
    const int r = t >> 6;                  // wave -> row (0..7)
    const float* xrow = &xs[r * E_IN];

    float aq0 = 0.f, aq1 = 0.f, ak0 = 0.f, ak1 = 0.f, av0 = 0.f, av1 = 0.f;
    #pragma unroll 8
    for (int e = 0; e < E_IN; e += 2) {
        float x0 = xrow[e], x1 = xrow[e + 1];
        aq0 += x0 * Wq[(e)     * D_QK   + d];
        aq1 += x1 * Wq[(e + 1) * D_QK   + d];
        ak0 += x0 * Wk[(e)     * D_QK   + d];
        ak1 += x1 * Wk[(e + 1) * D_QK   + d];
        av0 += x0 * Wv[(e)     * DV_OUT + d];
        av1 += x1 * Wv[(e + 1) * DV_OUT + d];
    }
    qs[r * D_QK + d] = fmaxf(aq0 + aq1 + bq[d], 0.f);
    ks[r * D_QK + d] = fmaxf(ak0 + ak1 + bk[d], 0.f);
    v[(size_t)(row0 + r) * DV_OUT + d] = av0 + av1 + bv[d];
    __syncthreads();

    const float* qrow = &qs[r * D_QK];
    const float* krow = &ks[r * D_QK];
    float ap0 = 0.f, ap1 = 0.f, bp0 = 0.f, bp1 = 0.f;
    #pragma unroll 8
    for (int e = 0; e < D_QK; e += 2) {
        ap0 += qrow[e]     * W1[(e)            * D_QK + d];
        ap1 += qrow[e + 1] * W1[(e + 1)        * D_QK + d];
        bp0 += krow[e]     * W1[(D_QK + e)     * D_QK + d];
        bp1 += krow[e + 1] * W1[(D_QK + e + 1) * D_QK + d];
    }
    qpb[(size_t)(row0 + r) * D_QK + d] = ap0 + ap1 + b1[d];
    kps[r * D_QK + d] = bp0 + bp1;
    __syncthreads();

    // transposed kp write: 8 consecutive rows = 32B per d
    if (t < D_QK) {
        float4 k0 = make_float4(kps[0 * D_QK + t], kps[1 * D_QK + t],
                                kps[2 * D_QK + t], kps[3 * D_QK + t]);
        float4 k1 = make_float4(kps[4 * D_QK + t], kps[5 * D_QK + t],
                                kps[6 * D_QK + t], kps[7 * D_QK + t]);
        *(float4*)&kpt[(size_t)t * NROWS + row0]     = k0;
        *(float4*)&kpt[(size_t)t * NROWS + row0 + 4] = k1;
    }
}

// ---------------------------------------------------------------------------
// Kernel 2: QT=4 queries per block ("query tile"), TRANSPOSED kp.
// Grid = B * 256 tiles = 512 blocks (2/CU). Tile swizzle pairs (c, 255-c) on
// consecutive blocks so any contiguous block window has ~constant work.
// Score loop per d: ONE float4 kp load (wave: 1KB contiguous) + one b128
// broadcast of qs[d][0..3] + one w2 read -> 48 VALU per 16B global load.
// Scores masked in registers; p stored to LDS as p[j][q] (b128); PV uses
// broadcast p + coalesced float2 v loads, 8 independent accumulators.
// ---------------------------------------------------------------------------
__global__ __launch_bounds__(256, 4) void attn_kernel(
    const float* __restrict__ qpb, const float* __restrict__ kpt,
    const float* __restrict__ v,
    const float* __restrict__ W2, const float* __restrict__ b2,
    float* __restrict__ out)
{
    __shared__ float qs[D_QK][QT];          // qs[d][q], row = 16B
    __shared__ float w2s[D_QK];
    __shared__ float p[T_CTX][QT];          // 16 KB, p[j][q]
    __shared__ float redm[4][QT], redl[4][QT];
    __shared__ float part[4][QT][DV_OUT];   // 4 KB

    const int blk  = blockIdx.x;
    const int b    = blk >> 8;
    const int u    = blk & 255;
    const int tile = (u & 1) ? (NTILES - 1 - (u >> 1)) : (u >> 1);
    const int i0   = tile * QT;
    const int nmax = i0 + QT;               // multiple of 4
    const int t    = threadIdx.x;
    const int lane = t & 63;
    const int wave = t >> 6;
    const size_t base = (size_t)b * T_CTX;

    // ---- stage q-tile (transposed into qs[d][q]) and w2 ----
    {
        const int q = t >> 6, d = t & 63;   // 256 threads = 4q x 64d exactly
        qs[d][q] = qpb[(base + i0 + q) * D_QK + d];
        if (t < D_QK) w2s[t] = W2[t];
    }
    __syncthreads();

    const float bias2 = b2[0];
    const int j0 = 4 * t;                   // thread owns j-quad [4t, 4t+3]
    const bool act = (j0 < nmax);

    float a[QT][4];
    #pragma unroll
    for (int q = 0; q < QT; ++q)
        #pragma unroll
        for (int jj = 0; jj < 4; ++jj) a[q][jj] = 0.f;

    if (act) {
        const float* kpb = kpt + base + j0;
        #pragma unroll 8
        for (int d = 0; d < D_QK; ++d) {
            float4 kv = *(const float4*)(kpb + (size_t)d * NROWS);
            float4 qv = *(const float4*)&qs[d][0];
            float wd  = w2s[d];
            float kvj[4] = {kv.x, kv.y, kv.z, kv.w};
            float qvq[4] = {qv.x, qv.y, qv.z, qv.w};
            #pragma unroll
            for (int q = 0; q < QT; ++q)
                #pragma unroll
                for (int jj = 0; jj < 4; ++jj)
                    a[q][jj] += fmaxf(qvq[q] + kvj[jj], 0.f) * wd;
        }
    }

    // ---- masked scores in registers ----
    float s[QT][4];
    #pragma unroll
    for (int q = 0; q < QT; ++q)
        #pragma unroll
        for (int jj = 0; jj < 4; ++jj)
            s[q][jj] = (j0 + jj <= i0 + q) ? bias2 + a[q][jj] : -INFINITY;

    // ---- per-query block max ----
    float ml[QT];
    #pragma unroll
    for (int q = 0; q < QT; ++q) {
        ml[q] = fmaxf(fmaxf(s[q][0], s[q][1]), fmaxf(s[q][2], s[q][3]));
        #pragma unroll
        for (int o = 32; o > 0; o >>= 1)
            ml[q] = fmaxf(ml[q], __shfl_xor(ml[q], o, 64));
    }
    if (lane == 0) {
        #pragma unroll
        for (int q = 0; q < QT; ++q) redm[wave][q] = ml[q];
    }
    __syncthreads();
    float m[QT];
    #pragma unroll
    for (int q = 0; q < QT; ++q)
        m[q] = fmaxf(fmaxf(redm[0][q], redm[1][q]),
                     fmaxf(redm[2][q], redm[3][q]));

    // ---- exp (registers) + p store + per-query block sum ----
    float pe[QT][4];
    float ls[QT] = {0.f, 0.f, 0.f, 0.f};
    #pragma unroll
    for (int q = 0; q < QT; ++q)
        #pragma unroll
        for (int jj = 0; jj < 4; ++jj) {
            float e = __expf(s[q][jj] - m[q]);   // masked -> exp(-inf)=0
            pe[q][jj] = e;
            ls[q] += e;
        }
    if (act) {
        #pragma unroll
        for (int jj = 0; jj < 4; ++jj)
            *(float4*)&p[j0 + jj][0] =
                make_float4(pe[0][jj], pe[1][jj], pe[2][jj], pe[3][jj]);
    }
    #pragma unroll
    for (int q = 0; q < QT; ++q) {
        #pragma unroll
        for (int o = 32; o > 0; o >>= 1)
            ls[q] += __shfl_xor(ls[q], o, 64);
    }
    if (lane == 0) {
        #pragma unroll
        for (int q = 0; q < QT; ++q) redl[wave][q] = ls[q];
    }
    __syncthreads();   // also makes p[] visible for PV

    // ---- PV: wave strides j (2 rows per iter via half-wave), float2 dv ----
    const int half = lane >> 5;
    const int dp   = (lane & 31) * 2;
    float accA[QT] = {0.f, 0.f, 0.f, 0.f};
    float accB[QT] = {0.f, 0.f, 0.f, 0.f};
    for (int j = wave * 2 + half; j < nmax; j += 8) {
        float4 pj = *(const float4*)&p[j][0];
        float2 vj = *(const float2*)&v[(base + j) * DV_OUT + dp];
        float pjq[4] = {pj.x, pj.y, pj.z, pj.w};
        #pragma unroll
        for (int q = 0; q < QT; ++q) {
            accA[q] += pjq[q] * vj.x;
            accB[q] += pjq[q] * vj.y;
        }
    }
    #pragma unroll
    for (int q = 0; q < QT; ++q) {
        accA[q] += __shfl_xor(accA[q], 32, 64);
        accB[q] += __shfl_xor(accB[q], 32, 64);
    }
    if (half == 0) {
        #pragma unroll
        for (int q = 0; q < QT; ++q)
            *(float2*)&part[wave][q][dp] = make_float2(accA[q], accB[q]);
    }
    __syncthreads();

    // ---- combine 4 waves + divide + store (coalesced) ----
    {
        const int q = t >> 6, dv = t & 63;
        float o = (part[0][q][dv] + part[1][q][dv]) +
                  (part[2][q][dv] + part[3][q][dv]);
        float den = (redl[0][q] + redl[1][q]) + (redl[2][q] + redl[3][q]);
        out[(base + i0 + q) * DV_OUT + dv] = o / den;
    }
}

extern "C" void kernel_launch(void* const* d_in, const int* in_sizes, int n_in,
                              void* d_out, int out_size, void* d_ws, size_t ws_size,
                              hipStream_t stream) {
    const float* x  = (const float*)d_in[0];
    const float* Wq = (const float*)d_in[1];
    const float* bq = (const float*)d_in[2];
    const float* Wk = (const float*)d_in[3];
    const float* bk = (const float*)d_in[4];
    const float* Wv = (const float*)d_in[5];
    const float* bv = (const float*)d_in[6];
    const float* W1 = (const float*)d_in[7];
    const float* b1 = (const float*)d_in[8];
    const float* W2 = (const float*)d_in[9];
    const float* b2 = (const float*)d_in[10];
    float* out = (float*)d_out;

    float* ws  = (float*)d_ws;
    float* qpb = ws;                              // NROWS * D_QK   (row-major)
    float* kpt = ws + (size_t)NROWS * D_QK;       // D_QK * NROWS   (TRANSPOSED)
    float* vv  = ws + (size_t)2 * NROWS * D_QK;   // NROWS * DV_OUT (row-major)

    proj_kernel<<<NROWS / RPB, 512, 0, stream>>>(x, Wq, bq, Wk, bk, Wv, bv,
                                                 W1, b1, qpb, kpt, vv);
    attn_kernel<<<B_SZ * NTILES, 256, 0, stream>>>(qpb, kpt, vv, W2, b2, out);
}

// Round 7
// 51.715 us; speedup vs baseline: 1.7602x; 1.4141x over previous
//
#include <hip/hip_runtime.h>

// Problem constants (match reference)
#define B_SZ   2
#define T_CTX  1024
#define E_IN   256
#define D_QK   64
#define DV_OUT 64
#define NROWS  (B_SZ * T_CTX)
#define RPB    8    // rows per proj block (one per wave, 512 threads)

// ---------------------------------------------------------------------------
// Kernel 1: projections, 8 rows per block, one row per wave (512 threads).
//   q = relu(x@Wq+bq); k = relu(x@Wk+bk); v = x@Wv+bv
//   qpb = q@W1[:64] + b1   (row-major [row][d])
//   kpt = (k@W1[64:])^T    (TRANSPOSED: [d][row])
// ---------------------------------------------------------------------------
__global__ __launch_bounds__(512) void proj_kernel(
    const float* __restrict__ x,
    const float* __restrict__ Wq, const float* __restrict__ bq,
    const float* __restrict__ Wk, const float* __restrict__ bk,
    const float* __restrict__ Wv, const float* __restrict__ bv,
    const float* __restrict__ W1, const float* __restrict__ b1,
    float* __restrict__ qpb, float* __restrict__ kpt, float* __restrict__ v)
{
    __shared__ float xs[RPB * E_IN];
    __shared__ float qs[RPB * D_QK];
    __shared__ float ks[RPB * D_QK];
    __shared__ float kps[RPB * D_QK];

    const int row0 = blockIdx.x * RPB;
    const int t    = threadIdx.x;

    *(float4*)&xs[4 * t] = *(const float4*)&x[(size_t)row0 * E_IN + 4 * t];
    __syncthreads();

    const int d = t & 63;
    const int r = t >> 6;                  // wave -> row (0..7)
    const float* xrow = &xs[r * E_IN];

    float aq0 = 0.f, aq1 = 0.f, ak0 = 0.f, ak1 = 0.f, av0 = 0.f, av1 = 0.f;
    #pragma unroll 8
    for (int e = 0; e < E_IN; e += 2) {
        float x0 = xrow[e], x1 = xrow[e + 1];
        aq0 += x0 * Wq[(e)     * D_QK   + d];
        aq1 += x1 * Wq[(e + 1) * D_QK   + d];
        ak0 += x0 * Wk[(e)     * D_QK   + d];
        ak1 += x1 * Wk[(e + 1) * D_QK   + d];
        av0 += x0 * Wv[(e)     * DV_OUT + d];
        av1 += x1 * Wv[(e + 1) * DV_OUT + d];
    }
    qs[r * D_QK + d] = fmaxf(aq0 + aq1 + bq[d], 0.f);
    ks[r * D_QK + d] = fmaxf(ak0 + ak1 + bk[d], 0.f);
    v[(size_t)(row0 + r) * DV_OUT + d] = av0 + av1 + bv[d];
    __syncthreads();

    const float* qrow = &qs[r * D_QK];
    const float* krow = &ks[r * D_QK];
    float ap0 = 0.f, ap1 = 0.f, bp0 = 0.f, bp1 = 0.f;
    #pragma unroll 8
    for (int e = 0; e < D_QK; e += 2) {
        ap0 += qrow[e]     * W1[(e)            * D_QK + d];
        ap1 += qrow[e + 1] * W1[(e + 1)        * D_QK + d];
        bp0 += krow[e]     * W1[(D_QK + e)     * D_QK + d];
        bp1 += krow[e + 1] * W1[(D_QK + e + 1) * D_QK + d];
    }
    qpb[(size_t)(row0 + r) * D_QK + d] = ap0 + ap1 + b1[d];
    kps[r * D_QK + d] = bp0 + bp1;
    __syncthreads();

    if (t < D_QK) {
        float4 k0 = make_float4(kps[0 * D_QK + t], kps[1 * D_QK + t],
                                kps[2 * D_QK + t], kps[3 * D_QK + t]);
        float4 k1 = make_float4(kps[4 * D_QK + t], kps[5 * D_QK + t],
                                kps[6 * D_QK + t], kps[7 * D_QK + t]);
        *(float4*)&kpt[(size_t)t * NROWS + row0]     = k0;
        *(float4*)&kpt[(size_t)t * NROWS + row0 + 4] = k1;
    }
}

// ---------------------------------------------------------------------------
// Kernel 2: tile-PAIR attention. Block c handles query rows A=[4c,4c+4) and
// B=[1020-4c,1024-4c): every block does IDENTICAL total work (257 j-quads),
// so no CU-level imbalance regardless of dispatch. Grid = 2*128 = 256 blocks
// = 1/CU, 512 threads.
//   Score: work unit = j-quad (4j x 8q x 64d); 2 threads split the d-range
//   (32 each) and fold with shfl_xor(1) -> ALL lanes fully busy, 48 VALU per
//   16B coalesced kpt float4 load.
//   psT[q][j] row-major per query: b128 writes ~8-way (vs 32-way before),
//   softmax reads conflict-free. Softmax: wave w owns q=w; waves w and w+4
//   share a SIMD with nA+nB=const -> SIMD-balanced.
//   PV: waves stride j-groups of 4; each v row read ONCE per block, feeds
//   all 8 queries (32 fma / 4 rows); per-wave partials combined in LDS.
// ---------------------------------------------------------------------------
__global__ __launch_bounds__(512, 2) void attn_kernel(
    const float* __restrict__ qpb, const float* __restrict__ kpt,
    const float* __restrict__ v,
    const float* __restrict__ W2, const float* __restrict__ b2,
    float* __restrict__ out)
{
    __shared__ float qqT[D_QK][8];          // [d][q8] 2KB
    __shared__ float w2s[D_QK];
    __shared__ float psT[8][T_CTX];         // 32KB: scores then weights
    __shared__ float denoms[8];
    __shared__ float part[8][8][DV_OUT];    // 16KB: wave x q x dv

    const int blk = blockIdx.x;
    const int b   = blk >> 7;
    const int c   = blk & 127;
    const int nA  = 4 * c + 4;
    const int nB  = T_CTX - 4 * c;
    const int rA0 = 4 * c;
    const int rB0 = T_CTX - 4 - 4 * c;
    const int t    = threadIdx.x;
    const int lane = t & 63;
    const int wave = t >> 6;
    const size_t base = (size_t)b * T_CTX;

    // ---- stage q-rows transposed + w2 ----
    {
        const int row = (wave < 4) ? (rA0 + wave) : (rB0 + wave - 4);
        qqT[lane][wave] = qpb[(base + row) * D_QK + lane];
        if (t < D_QK) w2s[t] = W2[t];
    }
    __syncthreads();

    const float bias2 = b2[0];

    // ---------------- score phase ----------------
    const int h  = t & 1;                   // d-half
    const int d0 = h << 5;
    for (int s = t >> 1; s < 257; s += 256) {
        int tile, j0, corner;
        if (s <= c)       { tile = 0; j0 = 4 * s;           corner = (s == c); }
        else if (s < 256) { tile = 1; j0 = 4 * (s - c - 1); corner = 0; }
        else              { tile = 1; j0 = 4 * (255 - c);   corner = 1; }

        float acc[4][4];
        #pragma unroll
        for (int q = 0; q < 4; ++q)
            #pragma unroll
            for (int jj = 0; jj < 4; ++jj) acc[q][jj] = 0.f;

        const float* kb = kpt + base + j0;
        #pragma unroll 8
        for (int dd = 0; dd < 32; ++dd) {
            const int d = d0 + dd;
            float4 kv = *(const float4*)(kb + (size_t)d * NROWS);
            float4 qv = *(const float4*)&qqT[d][tile << 2];
            float wd  = w2s[d];
            float kj[4] = {kv.x, kv.y, kv.z, kv.w};
            float qc[4] = {qv.x, qv.y, qv.z, qv.w};
            #pragma unroll
            for (int q = 0; q < 4; ++q)
                #pragma unroll
                for (int jj = 0; jj < 4; ++jj)
                    acc[q][jj] += fmaxf(qc[q] + kj[jj], 0.f) * wd;
        }
        // fold the two d-halves (partner = t^1, same s)
        #pragma unroll
        for (int q = 0; q < 4; ++q)
            #pragma unroll
            for (int jj = 0; jj < 4; ++jj)
                acc[q][jj] += __shfl_xor(acc[q][jj], 1, 64);

        if (h == 0) {
            #pragma unroll
            for (int q = 0; q < 4; ++q) {
                float4 sv;
                sv.x = (corner && 0 > q) ? -INFINITY : bias2 + acc[q][0];
                sv.y = (corner && 1 > q) ? -INFINITY : bias2 + acc[q][1];
                sv.z = (corner && 2 > q) ? -INFINITY : bias2 + acc[q][2];
                sv.w = (corner && 3 > q) ? -INFINITY : bias2 + acc[q][3];
                *(float4*)&psT[(tile << 2) + q][j0] = sv;
            }
        }
    }
    __syncthreads();

    // ---------------- softmax: wave w owns q = w ----------------
    {
        const int q = wave;
        const int n = (q < 4) ? nA : nB;
        float* row = psT[q];
        float sv[16];
        float m = -INFINITY;
        #pragma unroll
        for (int k = 0; k < 4; ++k) {
            const int j = 4 * lane + 256 * k;
            float4 xv = *(const float4*)&row[j];
            sv[4*k+0] = (j + 0 < n) ? xv.x : -INFINITY;
            sv[4*k+1] = (j + 1 < n) ? xv.y : -INFINITY;
            sv[4*k+2] = (j + 2 < n) ? xv.z : -INFINITY;
            sv[4*k+3] = (j + 3 < n) ? xv.w : -INFINITY;
            m = fmaxf(m, fmaxf(fmaxf(sv[4*k], sv[4*k+1]),
                               fmaxf(sv[4*k+2], sv[4*k+3])));
        }
        #pragma unroll
        for (int o = 32; o > 0; o >>= 1) m = fmaxf(m, __shfl_xor(m, o, 64));

        float sum = 0.f;
        #pragma unroll
        for (int k = 0; k < 4; ++k) {
            const int j = 4 * lane + 256 * k;
            float p0 = __expf(sv[4*k+0] - m);   // -inf -> 0
            float p1 = __expf(sv[4*k+1] - m);
            float p2 = __expf(sv[4*k+2] - m);
            float p3 = __expf(sv[4*k+3] - m);
            *(float4*)&row[j] = make_float4(p0, p1, p2, p3);
            sum += (p0 + p1) + (p2 + p3);
        }
        #pragma unroll
        for (int o = 32; o > 0; o >>= 1) sum += __shfl_xor(sum, o, 64);
        if (lane == 0) denoms[q] = sum;
    }
    __syncthreads();

    // ---------------- PV: waves stride j-groups of 4, shared v rows ----
    {
        const int dv = lane;
        float acc[8];
        #pragma unroll
        for (int q = 0; q < 8; ++q) acc[q] = 0.f;

        for (int jg = wave * 4; jg < nB; jg += 32) {
            float v0 = v[(base + jg + 0) * DV_OUT + dv];
            float v1 = v[(base + jg + 1) * DV_OUT + dv];
            float v2 = v[(base + jg + 2) * DV_OUT + dv];
            float v3 = v[(base + jg + 3) * DV_OUT + dv];
            #pragma unroll
            for (int q = 0; q < 8; ++q) {
                float4 pq = *(const float4*)&psT[q][jg];
                acc[q] += pq.x * v0 + pq.y * v1 + pq.z * v2 + pq.w * v3;
            }
        }
        #pragma unroll
        for (int q = 0; q < 8; ++q) part[wave][q][dv] = acc[q];
    }
    __syncthreads();

    // ---------------- epilogue: combine 8 wave-partials ----------------
    {
        const int q = wave, dv = lane;
        float s = 0.f;
        #pragma unroll
        for (int w = 0; w < 8; ++w) s += part[w][q][dv];
        const int row = (q < 4) ? (rA0 + q) : (rB0 + q - 4);
        out[(base + row) * DV_OUT + dv] = s / denoms[q];
    }
}

extern "C" void kernel_launch(void* const* d_in, const int* in_sizes, int n_in,
                              void* d_out, int out_size, void* d_ws, size_t ws_size,
                              hipStream_t stream) {
    const float* x  = (const float*)d_in[0];
    const float* Wq = (const float*)d_in[1];
    const float* bq = (const float*)d_in[2];
    const float* Wk = (const float*)d_in[3];
    const float* bk = (const float*)d_in[4];
    const float* Wv = (const float*)d_in[5];
    const float* bv = (const float*)d_in[6];
    const float* W1 = (const float*)d_in[7];
    const float* b1 = (const float*)d_in[8];
    const float* W2 = (const float*)d_in[9];
    const float* b2 = (const float*)d_in[10];
    float* out = (float*)d_out;

    float* ws  = (float*)d_ws;
    float* qpb = ws;                              // NROWS * D_QK   (row-major)
    float* kpt = ws + (size_t)NROWS * D_QK;       // D_QK * NROWS   (TRANSPOSED)
    float* vv  = ws + (size_t)2 * NROWS * D_QK;   // NROWS * DV_OUT (row-major)

    proj_kernel<<<NROWS / RPB, 512, 0, stream>>>(x, Wq, bq, Wk, bk, Wv, bv,
                                                 W1, b1, qpb, kpt, vv);
    attn_kernel<<<B_SZ * (T_CTX / 8), 512, 0, stream>>>(qpb, kpt, vv, W2, b2, out);
}

// Round 8
// 51.412 us; speedup vs baseline: 1.7705x; 1.0059x over previous
//
#include <hip/hip_runtime.h>

// Problem constants (match reference)
#define B_SZ   2
#define T_CTX  1024
#define E_IN   256
#define D_QK   64
#define DV_OUT 64
#define NROWS  (B_SZ * T_CTX)
#define CHUNK  128
#define SLOT_F 528                 // 8 m + 8 l + 8*64 pv
#define BLKS_PER_B 576             // sum over tiles of (tile/16 + 1)

// ---------------------------------------------------------------------------
// Kernel 1: projections. Each (row, d) output is computed by TWO threads
// (e-range halves, folded with shfl_xor(32)) -> 262K threads, 16 waves/CU.
// Block: 512 thr = 8 waves; wave w -> row r=w>>1, d-half dhi=w&1;
// lane: h=lane>>5 (e-half), d = dhi*32 + (lane&31). Grid = 512 (2/CU).
// ---------------------------------------------------------------------------
__global__ __launch_bounds__(512, 4) void proj_kernel(
    const float* __restrict__ x,
    const float* __restrict__ Wq, const float* __restrict__ bq,
    const float* __restrict__ Wk, const float* __restrict__ bk,
    const float* __restrict__ Wv, const float* __restrict__ bv,
    const float* __restrict__ W1, const float* __restrict__ b1,
    float* __restrict__ qpb, float* __restrict__ kpt, float* __restrict__ v)
{
    __shared__ float xs[4][E_IN];
    __shared__ float qs[4][D_QK];
    __shared__ float ks[4][D_QK];
    __shared__ float kps[4][D_QK];

    const int row0 = blockIdx.x * 4;
    const int t    = threadIdx.x;

    // stage 4 x-rows (1024 floats) via float2
    *(float2*)&(&xs[0][0])[2 * t] =
        *(const float2*)&x[(size_t)row0 * E_IN + 2 * t];
    __syncthreads();

    const int w    = t >> 6;
    const int r    = w >> 1;
    const int dhi  = w & 1;
    const int lane = t & 63;
    const int h    = lane >> 5;            // e-half
    const int d    = dhi * 32 + (lane & 31);
    const float* xrow = xs[r];
    const int e0 = h * 128;

    float aq = 0.f, ak = 0.f, av = 0.f;
    #pragma unroll 8
    for (int e = 0; e < 128; ++e) {
        float xv = xrow[e0 + e];
        aq += xv * Wq[(e0 + e) * D_QK   + d];
        ak += xv * Wk[(e0 + e) * D_QK   + d];
        av += xv * Wv[(e0 + e) * DV_OUT + d];
    }
    aq += __shfl_xor(aq, 32, 64);
    ak += __shfl_xor(ak, 32, 64);
    av += __shfl_xor(av, 32, 64);
    if (h == 0) {
        qs[r][d] = fmaxf(aq + bq[d], 0.f);
        ks[r][d] = fmaxf(ak + bk[d], 0.f);
        v[(size_t)(row0 + r) * DV_OUT + d] = av + bv[d];
    }
    __syncthreads();

    // stage 2: 64-deep sums, split 32/32 by h
    const int e1 = h * 32;
    float ap = 0.f, bp = 0.f;
    #pragma unroll 8
    for (int e = 0; e < 32; ++e) {
        ap += qs[r][e1 + e] * W1[(e1 + e) * D_QK + d];
        bp += ks[r][e1 + e] * W1[(D_QK + e1 + e) * D_QK + d];
    }
    ap += __shfl_xor(ap, 32, 64);
    bp += __shfl_xor(bp, 32, 64);
    if (h == 0) {
        qpb[(size_t)(row0 + r) * D_QK + d] = ap + b1[d];
        kps[r][d] = bp;
    }
    __syncthreads();

    if (t < D_QK) {
        float4 kq = make_float4(kps[0][t], kps[1][t], kps[2][t], kps[3][t]);
        *(float4*)&kpt[(size_t)t * NROWS + row0] = kq;
    }
}

// ---------------------------------------------------------------------------
// Kernel 2: partial attention. Block = (batch, 8-query tile, 128-j chunk).
// Grid = 2 * 576 = 1152 blocks, 256 threads, __launch_bounds__(256,8) so up
// to 8 blocks/CU co-reside (32 waves/CU). Identical dense work per block.
// Score: thread = (jl = t>>1, d-half h = t&1); 32 d-iters of 8q relu-dot;
// fold with shfl_xor(1). Partial softmax (block m,l) + partial PV ->
// workspace record {m[8], l[8], pv[8][64]}.
// ---------------------------------------------------------------------------
__global__ __launch_bounds__(256, 8) void attnA_kernel(
    const float* __restrict__ qpb, const float* __restrict__ kpt,
    const float* __restrict__ v,
    const float* __restrict__ W2, const float* __restrict__ b2,
    float* __restrict__ pws)
{
    __shared__ float qqT[D_QK][8];          // [d][q]
    __shared__ float w2s[D_QK];
    __shared__ float pT[CHUNK][8];          // weights, [jl][q]
    __shared__ float redm[4][8], redl[4][8];
    __shared__ float part[4][8][DV_OUT];    // 8KB

    // ---- decode block -> (b, tile, s) ----
    int u = blockIdx.x;
    int b = 0;
    if (u >= BLKS_PER_B) { b = 1; u -= BLKS_PER_B; }
    int a = 0;
    while (u >= 8 * (a + 1) * (a + 2)) ++a;     // group a: tiles 16a..16a+15
    const int local = u - 8 * a * (a + 1);
    const int tidx  = local / (a + 1);
    const int s     = local - tidx * (a + 1);
    const int tile  = 16 * a + tidx;
    const int i0    = tile * 8;
    const int jc    = s * CHUNK;

    const int t    = threadIdx.x;
    const int lane = t & 63;
    const int wv   = t >> 6;
    const size_t base = (size_t)b * T_CTX;

    // ---- stage q-tile (transposed) + w2 ----
    for (int k = t; k < 512; k += 256)
        qqT[k & 63][k >> 6] = qpb[(base + i0 + (k >> 6)) * D_QK + (k & 63)];
    if (t < D_QK) w2s[t] = W2[t];
    __syncthreads();

    const float bias2 = b2[0];

    // ---- score: 8 queries x this thread's j, over 32 d ----
    const int jl = t >> 1;
    const int h  = t & 1;
    const int j  = jc + jl;
    const int d0 = h * 32;
    float acc[8];
    #pragma unroll
    for (int q = 0; q < 8; ++q) acc[q] = 0.f;

    const float* kcol = kpt + (size_t)d0 * NROWS + base + j;
    #pragma unroll 8
    for (int dd = 0; dd < 32; ++dd) {
        float kv = kcol[(size_t)dd * NROWS];
        float4 qa = *(const float4*)&qqT[d0 + dd][0];
        float4 qb = *(const float4*)&qqT[d0 + dd][4];
        float wd  = w2s[d0 + dd];
        acc[0] += fmaxf(qa.x + kv, 0.f) * wd;
        acc[1] += fmaxf(qa.y + kv, 0.f) * wd;
        acc[2] += fmaxf(qa.z + kv, 0.f) * wd;
        acc[3] += fmaxf(qa.w + kv, 0.f) * wd;
        acc[4] += fmaxf(qb.x + kv, 0.f) * wd;
        acc[5] += fmaxf(qb.y + kv, 0.f) * wd;
        acc[6] += fmaxf(qb.z + kv, 0.f) * wd;
        acc[7] += fmaxf(qb.w + kv, 0.f) * wd;
    }
    #pragma unroll
    for (int q = 0; q < 8; ++q) acc[q] += __shfl_xor(acc[q], 1, 64);

    // ---- masked scores + wave max ----
    float sv[8], mw;
    #pragma unroll
    for (int q = 0; q < 8; ++q)
        sv[q] = (j <= i0 + q) ? bias2 + acc[q] : -INFINITY;
    #pragma unroll
    for (int q = 0; q < 8; ++q) {
        mw = sv[q];
        #pragma unroll
        for (int o = 32; o > 0; o >>= 1) mw = fmaxf(mw, __shfl_xor(mw, o, 64));
        if (lane == 0) redm[wv][q] = mw;
    }
    __syncthreads();

    float m[8];
    #pragma unroll
    for (int q = 0; q < 8; ++q)
        m[q] = fmaxf(fmaxf(redm[0][q], redm[1][q]),
                     fmaxf(redm[2][q], redm[3][q]));

    // ---- exp + store weights + wave sum (h==0 lanes only contribute) ----
    float pe[8];
    #pragma unroll
    for (int q = 0; q < 8; ++q) pe[q] = __expf(sv[q] - m[q]);  // -inf -> 0
    if (h == 0) {
        *(float4*)&pT[jl][0] = make_float4(pe[0], pe[1], pe[2], pe[3]);
        *(float4*)&pT[jl][4] = make_float4(pe[4], pe[5], pe[6], pe[7]);
    }
    #pragma unroll
    for (int q = 0; q < 8; ++q) {
        float ls = (h == 0) ? pe[q] : 0.f;
        #pragma unroll
        for (int o = 32; o > 0; o >>= 1) ls += __shfl_xor(ls, o, 64);
        if (lane == 0) redl[wv][q] = ls;
    }
    __syncthreads();

    // ---- write m, l records ----
    const size_t sb = ((size_t)(b * 128 + tile) * 8 + s) * SLOT_F;
    if (t < 8) {
        float mv = fmaxf(fmaxf(redm[0][t], redm[1][t]),
                         fmaxf(redm[2][t], redm[3][t]));
        float lv = (redl[0][t] + redl[1][t]) + (redl[2][t] + redl[3][t]);
        pws[sb + t]     = mv;
        pws[sb + 8 + t] = lv;
    }

    // ---- partial PV: wave wv handles 32 j-rows; dv = lane ----
    {
        const int dv = lane;
        float av[8];
        #pragma unroll
        for (int q = 0; q < 8; ++q) av[q] = 0.f;
        const int j0w = wv * 32;
        #pragma unroll 4
        for (int k = 0; k < 32; ++k) {
            const int jr = j0w + k;
            float vval = v[(base + jc + jr) * DV_OUT + dv];
            float4 pa = *(const float4*)&pT[jr][0];
            float4 pb = *(const float4*)&pT[jr][4];
            av[0] += pa.x * vval; av[1] += pa.y * vval;
            av[2] += pa.z * vval; av[3] += pa.w * vval;
            av[4] += pb.x * vval; av[5] += pb.y * vval;
            av[6] += pb.z * vval; av[7] += pb.w * vval;
        }
        #pragma unroll
        for (int q = 0; q < 8; ++q) part[wv][q][dv] = av[q];
    }
    __syncthreads();

    // ---- combine 4 wave-partials, write pv record (coalesced) ----
    #pragma unroll
    for (int k = 0; k < 2; ++k) {
        const int idx = t + 256 * k;
        const int q = idx >> 6, dv = idx & 63;
        float val = (part[0][q][dv] + part[1][q][dv]) +
                    (part[2][q][dv] + part[3][q][dv]);
        pws[sb + 16 + idx] = val;
    }
}

// ---------------------------------------------------------------------------
// Kernel 3: combine split partials with online-softmax rescaling.
// Block = (b, tile); 512 thr: wave = q, lane = dv. nsp = tile/16 + 1 <= 8.
// ---------------------------------------------------------------------------
__global__ __launch_bounds__(512) void combine_kernel(
    const float* __restrict__ pws, float* __restrict__ out)
{
    const int blk  = blockIdx.x;
    const int b    = blk >> 7;
    const int tile = blk & 127;
    const int nsp  = (tile >> 4) + 1;
    const size_t sb0 = (size_t)(b * 128 + tile) * 8 * SLOT_F;

    const int t  = threadIdx.x;
    const int q  = t >> 6;
    const int dv = t & 63;

    float M = -INFINITY;
    for (int s = 0; s < nsp; ++s)
        M = fmaxf(M, pws[sb0 + (size_t)s * SLOT_F + q]);

    float L = 0.f, acc = 0.f;
    for (int s = 0; s < nsp; ++s) {
        const size_t sb = sb0 + (size_t)s * SLOT_F;
        float ms = pws[sb + q];
        float ls = pws[sb + 8 + q];
        float sc = __expf(ms - M);
        L   += ls * sc;
        acc += pws[sb + 16 + q * 64 + dv] * sc;
    }
    out[((size_t)b * T_CTX + tile * 8 + q) * DV_OUT + dv] = acc / L;
}

extern "C" void kernel_launch(void* const* d_in, const int* in_sizes, int n_in,
                              void* d_out, int out_size, void* d_ws, size_t ws_size,
                              hipStream_t stream) {
    const float* x  = (const float*)d_in[0];
    const float* Wq = (const float*)d_in[1];
    const float* bq = (const float*)d_in[2];
    const float* Wk = (const float*)d_in[3];
    const float* bk = (const float*)d_in[4];
    const float* Wv = (const float*)d_in[5];
    const float* bv = (const float*)d_in[6];
    const float* W1 = (const float*)d_in[7];
    const float* b1 = (const float*)d_in[8];
    const float* W2 = (const float*)d_in[9];
    const float* b2 = (const float*)d_in[10];
    float* out = (float*)d_out;

    float* ws  = (float*)d_ws;
    float* qpb = ws;                               // NROWS*64
    float* kpt = ws + (size_t)NROWS * D_QK;        // 64*NROWS (transposed)
    float* vv  = ws + (size_t)2 * NROWS * D_QK;    // NROWS*64
    float* pws = ws + (size_t)3 * NROWS * D_QK;    // 2048 slots * SLOT_F

    proj_kernel<<<NROWS / 4, 512, 0, stream>>>(x, Wq, bq, Wk, bk, Wv, bv,
                                               W1, b1, qpb, kpt, vv);
    attnA_kernel<<<B_SZ * BLKS_PER_B, 256, 0, stream>>>(qpb, kpt, vv, W2, b2,
                                                        pws);
    combine_kernel<<<B_SZ * (T_CTX / 8), 512, 0, stream>>>(pws, out);
}